// Round 11
// baseline (1386.504 us; speedup 1.0000x reference)
//
#include <hip/hip_runtime.h>
#include <hip/hip_bf16.h>
#include <cstdint>

// MoEExperts: x[4096,2048] f32, top-2 of 8 experts,
// w1/w3 [8,2048,4096] (K-major [K][N]), w2 [8,4096,2048], out [4096,2048] f32.
#define T_TOKENS 4096
#define HID      2048
#define INTER    4096
#define NEXP     8
#define TOPK     2
#define NPAIRS   (T_TOKENS * TOPK)          // 8192
#define BM 128
#define BN 128
#define BK 32
#define MAXROWS  (NPAIRS + NEXP * BM)       // 9216
#define NRB1     64                          // worst-case per-expert row-blocks

typedef __attribute__((ext_vector_type(8))) short   short8;
typedef __attribute__((ext_vector_type(4))) float   f32x4;
typedef __attribute__((ext_vector_type(8))) ushort  ushort8v;

static __device__ __forceinline__ ushort f2bf(float f) {
    __hip_bfloat16 b = __float2bfloat16(f);
    return __builtin_bit_cast(ushort, b);
}

typedef const __attribute__((address_space(1))) unsigned char ga_u8;
typedef __attribute__((address_space(3))) unsigned char       la_u8;
static __device__ __forceinline__ void gl_lds16(const void* g, void* l) {
    __builtin_amdgcn_global_load_lds((ga_u8*)g, (la_u8*)l, 16, 0, 0);
}

// ---------------- routing -------------------------------------------------
__global__ void route_kernel(const int* __restrict__ eidx,
                             const float* __restrict__ ew,
                             int* __restrict__ cnt, int* __restrict__ pbase,
                             int* __restrict__ ctrs,
                             int* __restrict__ tokl, float* __restrict__ wgtl,
                             int* __restrict__ pairrow) {
    __shared__ int s_cnt[NEXP];
    __shared__ int s_pos[NEXP];
    __shared__ int s_base[NEXP];
    int tid = threadIdx.x;
    if (tid < NEXP) { s_cnt[tid] = 0; s_pos[tid] = 0; }
    if (tid < 8) ctrs[tid] = 0;
    __syncthreads();
    for (int p = tid; p < NPAIRS; p += blockDim.x)
        atomicAdd(&s_cnt[eidx[p]], 1);
    __syncthreads();
    if (tid == 0) {
        int b = 0;
        for (int e = 0; e < NEXP; ++e) {
            s_base[e] = b;
            cnt[e]    = s_cnt[e];
            pbase[e]  = b;
            b += (s_cnt[e] + BM - 1) / BM * BM;
        }
        pbase[NEXP] = b;
    }
    __syncthreads();
    for (int p = tid; p < NPAIRS; p += blockDim.x) {
        int e   = eidx[p];
        int pos = atomicAdd(&s_pos[e], 1);
        int row = s_base[e] + pos;
        tokl[row]  = p >> 1;
        wgtl[row]  = ew[p];
        pairrow[p] = row;
    }
}

// ---------------- x fp32 -> bf16 ------------------------------------------
__global__ __launch_bounds__(256) void cvt_x_kernel(const float* __restrict__ x,
                                                    ushort* __restrict__ xbf) {
    int i = (blockIdx.x * 256 + threadIdx.x) * 8;
    float4 a = *reinterpret_cast<const float4*>(x + i);
    float4 b = *reinterpret_cast<const float4*>(x + i + 4);
    ushort8v o;
    o[0] = f2bf(a.x); o[1] = f2bf(a.y); o[2] = f2bf(a.z); o[3] = f2bf(a.w);
    o[4] = f2bf(b.x); o[5] = f2bf(b.y); o[6] = f2bf(b.z); o[7] = f2bf(b.w);
    *reinterpret_cast<ushort8v*>(xbf + i) = o;
}

// ---------------- 64x64 transpose+convert tile (device helper) -------------
// src fp32 [K][N] tile at (kb,nb) -> dst bf16 [N][K]
static __device__ void trans_tile(const float* __restrict__ s, ushort* __restrict__ d,
                                  int K, int N, int tile, ushort (*t)[72]) {
    int nb = (tile % (N >> 6)) << 6;
    int kb = (tile / (N >> 6)) << 6;
    int tid = threadIdx.x;
    int kr = tid >> 2;
    int ns = tid & 3;
    #pragma unroll
    for (int p = 0; p < 4; ++p) {
        int f = ns + p * 4;
        float4 v = *reinterpret_cast<const float4*>(&s[(size_t)(kb + kr) * N + nb + f * 4]);
        t[f * 4 + 0][kr] = f2bf(v.x);
        t[f * 4 + 1][kr] = f2bf(v.y);
        t[f * 4 + 2][kr] = f2bf(v.z);
        t[f * 4 + 3][kr] = f2bf(v.w);
    }
    __syncthreads();
    int nr = tid >> 2;
    #pragma unroll
    for (int p = 0; p < 2; ++p) {
        int ks = ((tid & 3) + p * 4) * 8;
        ushort8v v8 = *reinterpret_cast<const ushort8v*>(&t[nr][ks]);
        *reinterpret_cast<ushort8v*>(&d[(size_t)(nb + nr) * K + kb + ks]) = v8;
    }
    __syncthreads();
}

// ---------------- standalone transpose kernel (serial seed) ----------------
__global__ __launch_bounds__(256) void transpose_cvt_kernel(
        const float* __restrict__ src, ushort* __restrict__ dst,
        int K, int N, long estride) {
    __shared__ ushort t[64][72];
    int ez = blockIdx.z;
    trans_tile(src + (size_t)ez * estride, dst + (size_t)ez * (size_t)N * K,
               K, N, blockIdx.y * (N >> 6) + blockIdx.x, t);
}

// swizzle helper: spreads 16B slots across banks; bijective per row
#define SWZV(r) (((r) & 3) ^ (((r) >> 2) & 3))

// ---------------- ffn1: h = silu(x@w1) * (x@w3); dead blocks transpose -----
#define F1_LDSB 24576   // per dbuf: A 8KB + B1 8KB + B3 8KB
__global__ __launch_bounds__(256, 2) void ffn1_kernel(
        const ushort* __restrict__ xbf,
        const ushort* __restrict__ wT1, const ushort* __restrict__ wT3,
        const int* __restrict__ cnt, const int* __restrict__ pbase,
        const int* __restrict__ tokl, ushort* __restrict__ h,
        int e0, int CN, int c0,
        const float* __restrict__ j1w1, const float* __restrict__ j1w3,
        ushort* __restrict__ j1dst, int j1ne,
        const float* __restrict__ j2src, ushort* __restrict__ j2dst, int j2ne,
        int* __restrict__ ctr) {
    __shared__ ushort ldsbuf[2 * F1_LDSB / 2];
    __shared__ ushort tw[64][72];
    __shared__ int s_id;

    int d = blockIdx.x;
    int xcd = d & 7, q = d >> 3;
    int gq = q / NRB1, rb = q % NRB1;
    int ncb = CN >> 7;
    int g = gq * 8 + xcd;
    int ez = g / ncb, cb = g - ez * ncb;
    int e = e0 + ez;
    int ce = cnt[e];
    int r0 = rb * BM;
    int tid = threadIdx.x;
    if (r0 >= ce) {
        // ---------- transpose worker: ONE queue pop per BLOCK ----------
        const int tpm = (HID >> 6) * (INTER >> 6);   // 2048 tiles / matrix
        int n1 = j1ne * 2 * tpm;
        int n2 = j2ne * tpm;
        int tot = n1 + n2;
        if (tot == 0) return;
        for (;;) {
            if (tid == 0) s_id = atomicAdd(ctr, 1);
            __syncthreads();
            int id = s_id;                 // uniform across block
            if (id >= tot) return;
            if (id < n1) {
                int m = id / tpm, r = id % tpm;
                const float* src = (m < j1ne ? j1w1 + (size_t)m * HID * INTER
                                             : j1w3 + (size_t)(m - j1ne) * HID * INTER);
                trans_tile(src, j1dst + (size_t)m * INTER * HID, HID, INTER, r, tw);
            } else {
                int id2 = id - n1;
                int m = id2 / tpm, r = id2 % tpm;
                trans_tile(j2src + (size_t)m * INTER * HID,
                           j2dst + (size_t)m * (size_t)HID * INTER, INTER, HID, r, tw);
            }
            // trans_tile ends with __syncthreads(): safe to overwrite s_id
        }
    }
    int base = pbase[e];

    int lane = tid & 63, wid = tid >> 6;
    int wr = (wid >> 1) * 64, wc = (wid & 1) * 64;

    int t0 = wid * 32 + (lane >> 2);
    int t1 = t0 + 16;
    int sw0 = (((lane & 3) ^ SWZV(t0)) << 4);
    int sw1 = (((lane & 3) ^ SWZV(t1)) << 4);
    int cr0 = r0 + t0, cr1 = r0 + t1;
    const char* aS0 = (const char*)(xbf + (size_t)tokl[base + (cr0 < ce ? cr0 : 0)] * HID) + sw0;
    const char* aS1 = (const char*)(xbf + (size_t)tokl[base + (cr1 < ce ? cr1 : 0)] * HID) + sw1;
    const ushort* B1g = wT1 + ((size_t)ez * CN + (size_t)cb * 128) * HID;
    const ushort* B3g = wT3 + ((size_t)ez * CN + (size_t)cb * 128) * HID;
    const char* b1S0 = (const char*)(B1g + (size_t)t0 * HID) + sw0;
    const char* b1S1 = (const char*)(B1g + (size_t)t1 * HID) + sw1;
    const char* b3S0 = (const char*)(B3g + (size_t)t0 * HID) + sw0;
    const char* b3S1 = (const char*)(B3g + (size_t)t1 * HID) + sw1;

    char* Lb = (char*)ldsbuf;
    int dst0 = wid * 2048;

    int vl = SWZV(lane & 15);
    int fs = (((lane >> 4) ^ vl) << 4);
    int aoff[4], boff[4];
    #pragma unroll
    for (int i = 0; i < 4; ++i) {
        aoff[i] = (wr + i * 16 + (lane & 15)) * 64 + fs;
        boff[i] = (wc + i * 16 + (lane & 15)) * 64 + fs;
    }

    f32x4 accg[4][4], accu[4][4];
    #pragma unroll
    for (int i = 0; i < 4; ++i)
        #pragma unroll
        for (int j = 0; j < 4; ++j) { accg[i][j] = (f32x4)0.f; accu[i][j] = (f32x4)0.f; }

    auto stage = [&](int buf, int t) {
        char* L = Lb + buf * F1_LDSB;
        int adv = t * 64;
        gl_lds16(aS0 + adv,  L + dst0);
        gl_lds16(aS1 + adv,  L + dst0 + 1024);
        gl_lds16(b1S0 + adv, L + 8192 + dst0);
        gl_lds16(b1S1 + adv, L + 8192 + dst0 + 1024);
        gl_lds16(b3S0 + adv, L + 16384 + dst0);
        gl_lds16(b3S1 + adv, L + 16384 + dst0 + 1024);
    };

    stage(0, 0);
    __syncthreads();
    const int NT = HID / BK;
    for (int t = 0; t < NT; ++t) {
        int cur = t & 1;
        if (t + 1 < NT) stage(cur ^ 1, t + 1);
        const char* L = Lb + cur * F1_LDSB;
        short8 af[4];
        #pragma unroll
        for (int mi = 0; mi < 4; ++mi)
            af[mi] = *reinterpret_cast<const short8*>(L + aoff[mi]);
        #pragma unroll
        for (int ni = 0; ni < 4; ++ni) {
            short8 b1 = *reinterpret_cast<const short8*>(L + 8192 + boff[ni]);
            short8 b3 = *reinterpret_cast<const short8*>(L + 16384 + boff[ni]);
            #pragma unroll
            for (int mi = 0; mi < 4; ++mi) {
                accg[mi][ni] = __builtin_amdgcn_mfma_f32_16x16x32_bf16(af[mi], b1, accg[mi][ni], 0, 0, 0);
                accu[mi][ni] = __builtin_amdgcn_mfma_f32_16x16x32_bf16(af[mi], b3, accu[mi][ni], 0, 0, 0);
            }
        }
        __syncthreads();
    }

    int hcol = c0 + cb * 128 + wc + (lane & 15);
    #pragma unroll
    for (int mi = 0; mi < 4; ++mi) {
        #pragma unroll
        for (int q2 = 0; q2 < 4; ++q2) {
            int r = r0 + wr + mi * 16 + (lane >> 4) * 4 + q2;
            if (r >= ce) continue;
            ushort* hp = h + (size_t)(base + r) * INTER + hcol;
            #pragma unroll
            for (int ni = 0; ni < 4; ++ni) {
                float gg = accg[mi][ni][q2];
                float uu = accu[mi][ni][q2];
                float s = gg / (1.f + __expf(-gg));
                hp[ni * 16] = f2bf(s * uu);
            }
        }
    }
}

// ---------------- ffn2: y = wgt * (h @ w2) ---------------------------------
#define F2_LDSB 16384   // per dbuf: A 8KB + B 8KB
__global__ __launch_bounds__(256, 3) void ffn2_kernel(
        const ushort* __restrict__ h,
        const ushort* __restrict__ wT2,
        const int* __restrict__ cnt, const int* __restrict__ pbase,
        const float* __restrict__ wgtl, ushort* __restrict__ y,
        int e0, int CN, int c0) {
    int d = blockIdx.x;
    int xcd = d & 7, q = d >> 3;
    int gq = q / NRB1, rb = q % NRB1;
    int ncb = CN >> 7;
    int g = gq * 8 + xcd;
    int ez = g / ncb, cb = g - ez * ncb;
    int e = e0 + ez;
    int ce = cnt[e];
    int r0 = rb * BM;
    if (r0 >= ce) return;
    int base = pbase[e];

    __shared__ ushort ldsbuf[2 * F2_LDSB / 2];
    int tid = threadIdx.x, lane = tid & 63, wid = tid >> 6;
    int wr = (wid >> 1) * 64, wc = (wid & 1) * 64;

    int t0 = wid * 32 + (lane >> 2);
    int t1 = t0 + 16;
    int sw0 = (((lane & 3) ^ SWZV(t0)) << 4);
    int sw1 = (((lane & 3) ^ SWZV(t1)) << 4);
    int cr0 = r0 + t0, cr1 = r0 + t1;
    const char* aS0 = (const char*)(h + (size_t)(base + (cr0 < ce ? cr0 : 0)) * INTER) + sw0;
    const char* aS1 = (const char*)(h + (size_t)(base + (cr1 < ce ? cr1 : 0)) * INTER) + sw1;
    const ushort* Bg = wT2 + ((size_t)ez * CN + (size_t)cb * 128) * INTER;
    const char* bS0 = (const char*)(Bg + (size_t)t0 * INTER) + sw0;
    const char* bS1 = (const char*)(Bg + (size_t)t1 * INTER) + sw1;

    char* Lb = (char*)ldsbuf;
    int dst0 = wid * 2048;

    int vl = SWZV(lane & 15);
    int fs = (((lane >> 4) ^ vl) << 4);
    int aoff[4], boff[4];
    #pragma unroll
    for (int i = 0; i < 4; ++i) {
        aoff[i] = (wr + i * 16 + (lane & 15)) * 64 + fs;
        boff[i] = (wc + i * 16 + (lane & 15)) * 64 + fs;
    }

    f32x4 acc[4][4];
    #pragma unroll
    for (int i = 0; i < 4; ++i)
        #pragma unroll
        for (int j = 0; j < 4; ++j) acc[i][j] = (f32x4)0.f;

    auto stage = [&](int buf, int t) {
        char* L = Lb + buf * F2_LDSB;
        int adv = t * 64;
        gl_lds16(aS0 + adv, L + dst0);
        gl_lds16(aS1 + adv, L + dst0 + 1024);
        gl_lds16(bS0 + adv, L + 8192 + dst0);
        gl_lds16(bS1 + adv, L + 8192 + dst0 + 1024);
    };

    stage(0, 0);
    __syncthreads();
    const int NT = INTER / BK;
    for (int t = 0; t < NT; ++t) {
        int cur = t & 1;
        if (t + 1 < NT) stage(cur ^ 1, t + 1);
        const char* L = Lb + cur * F2_LDSB;
        short8 af[4];
        #pragma unroll
        for (int mi = 0; mi < 4; ++mi)
            af[mi] = *reinterpret_cast<const short8*>(L + aoff[mi]);
        #pragma unroll
        for (int ni = 0; ni < 4; ++ni) {
            short8 b = *reinterpret_cast<const short8*>(L + 8192 + boff[ni]);
            #pragma unroll
            for (int mi = 0; mi < 4; ++mi)
                acc[mi][ni] = __builtin_amdgcn_mfma_f32_16x16x32_bf16(af[mi], b, acc[mi][ni], 0, 0, 0);
        }
        __syncthreads();
    }

    int ycol = c0 + cb * 128 + wc + (lane & 15);
    #pragma unroll
    for (int mi = 0; mi < 4; ++mi) {
        #pragma unroll
        for (int q2 = 0; q2 < 4; ++q2) {
            int r = r0 + wr + mi * 16 + (lane >> 4) * 4 + q2;
            if (r >= ce) continue;
            float wv = wgtl[base + r];
            ushort* yp = y + (size_t)(base + r) * HID + ycol;
            #pragma unroll
            for (int ni = 0; ni < 4; ++ni)
                yp[ni * 16] = f2bf(wv * acc[mi][ni][q2]);
        }
    }
}

// ---------------- combine --------------------------------------------------
__global__ __launch_bounds__(256) void combine_kernel(
        const ushort* __restrict__ y, const int* __restrict__ pairrow,
        float* __restrict__ out) {
    int t = blockIdx.x;
    const ushort* y0 = y + (size_t)pairrow[2 * t] * HID;
    const ushort* y1 = y + (size_t)pairrow[2 * t + 1] * HID;
    float* op = out + (size_t)t * HID;
    int c = threadIdx.x * 8;
    uint4 a = *reinterpret_cast<const uint4*>(y0 + c);
    uint4 b = *reinterpret_cast<const uint4*>(y1 + c);
    const uint* au = reinterpret_cast<const uint*>(&a);
    const uint* bu = reinterpret_cast<const uint*>(&b);
    #pragma unroll
    for (int i = 0; i < 4; ++i) {
        float alo = __builtin_bit_cast(float, au[i] << 16);
        float ahi = __builtin_bit_cast(float, au[i] & 0xffff0000u);
        float blo = __builtin_bit_cast(float, bu[i] << 16);
        float bhi = __builtin_bit_cast(float, bu[i] & 0xffff0000u);
        op[c + 2 * i]     = alo + blo;
        op[c + 2 * i + 1] = ahi + bhi;
    }
}

extern "C" void kernel_launch(void* const* d_in, const int* in_sizes, int n_in,
                              void* d_out, int out_size, void* d_ws, size_t ws_size,
                              hipStream_t stream) {
    (void)in_sizes; (void)n_in; (void)out_size;
    const float* x   = (const float*)d_in[0];
    const float* ew  = (const float*)d_in[1];
    const float* w1  = (const float*)d_in[2];
    const float* w2  = (const float*)d_in[3];
    const float* w3  = (const float*)d_in[4];
    const int*  eidx = (const int*)d_in[5];
    float* out = (float*)d_out;

    int*   cnt     = (int*)d_ws;
    int*   pbase   = cnt + 8;                 // 9
    int*   ctrs    = cnt + 20;                // 8
    int*   tokl    = cnt + 32;
    float* wgtl    = (float*)(tokl + MAXROWS);
    int*   pairrow = (int*)(wgtl + MAXROWS);
    ushort* xbf = (ushort*)((((uintptr_t)(pairrow + NPAIRS)) + 255) & ~(uintptr_t)255);
    ushort* h   = xbf + (size_t)T_TOKENS * HID;
    ushort* y   = h + (size_t)MAXROWS * INTER;
    ushort* region = y + (size_t)MAXROWS * HID;
    size_t region_bytes = ws_size - ((char*)region - (char*)d_ws);

    const size_t IH = (size_t)INTER * HID;           // elements per matrix
    const long   ES = (long)HID * INTER;             // expert stride (elements)

    route_kernel<<<1, 256, 0, stream>>>(eidx, ew, cnt, pbase, ctrs, tokl, wgtl, pairrow);
    cvt_x_kernel<<<T_TOKENS * HID / 8 / 256, 256, 0, stream>>>(x, xbf);

    const size_t GRP = 4 * IH * sizeof(ushort);      // 2-expert w1T+w3T group: 67.1 MB
    const size_t WC  = 8 * IH * sizeof(ushort);      // all-expert w2T: 134.2 MB

    if (region_bytes >= 2 * GRP + WC) {
        // ---- pipelined path: workers inside ffn1 hide all remaining transposes
        ushort* bufA = region;
        ushort* bufB = region + 4 * IH;
        ushort* bufC = region + 8 * IH;

        // serial seed: w1/w3 of experts 0,1 -> bufA
        transpose_cvt_kernel<<<dim3(INTER / 64, HID / 64, 2), 256, 0, stream>>>(
            w1, bufA, HID, INTER, ES);
        transpose_cvt_kernel<<<dim3(INTER / 64, HID / 64, 2), 256, 0, stream>>>(
            w3, bufA + 2 * IH, HID, INTER, ES);

        for (int s = 0; s < 4; ++s) {
            int e0 = 2 * s;
            ushort* buf = (s & 1) ? bufB : bufA;
            ushort* nxt = (s & 1) ? bufA : bufB;
            int j1ne = (s < 3) ? 2 : 0;
            const float* j1w1 = w1 + (size_t)(e0 + 2) * IH;
            const float* j1w3 = w3 + (size_t)(e0 + 2) * IH;
            const float* j2s  = w2 + (size_t)e0 * IH;
            ushort* j2d = bufC + (size_t)e0 * IH;
            ffn1_kernel<<<NRB1 * 2 * (INTER / BN), 256, 0, stream>>>(
                xbf, buf, buf + 2 * IH, cnt, pbase, tokl, h, e0, INTER, 0,
                j1w1, j1w3, nxt, j1ne, j2s, j2d, 2, ctrs + s);
        }
        ffn2_kernel<<<NRB1 * 8 * (HID / BN), 256, 0, stream>>>(
            h, bufC, cnt, pbase, wgtl, y, 0, HID, 0);
    } else {
        // ---- fallback: serial transpose + GEMM, expert-grouped (R6 flow)
        const size_t per_e1 = 2 * IH * sizeof(ushort);
        const size_t per_e2 = IH * sizeof(ushort);
        int EG1 = (int)(region_bytes / per_e1); if (EG1 > 8) EG1 = 8; if (EG1 < 1) EG1 = 1;
        for (int g = 0; g < NEXP; g += EG1) {
            int ne = (NEXP - g < EG1) ? (NEXP - g) : EG1;
            ushort* wt1 = region;
            ushort* wt3 = region + (size_t)ne * IH;
            transpose_cvt_kernel<<<dim3(INTER / 64, HID / 64, ne), 256, 0, stream>>>(
                w1 + (size_t)g * IH, wt1, HID, INTER, ES);
            transpose_cvt_kernel<<<dim3(INTER / 64, HID / 64, ne), 256, 0, stream>>>(
                w3 + (size_t)g * IH, wt3, HID, INTER, ES);
            ffn1_kernel<<<NRB1 * ne * (INTER / BN), 256, 0, stream>>>(
                xbf, wt1, wt3, cnt, pbase, tokl, h, g, INTER, 0,
                w1, w3, region, 0, w2, region, 0, ctrs + 7);
        }
        int EG2 = (int)(region_bytes / per_e2); if (EG2 > 8) EG2 = 8; if (EG2 < 1) EG2 = 1;
        for (int g = 0; g < NEXP; g += EG2) {
            int ne = (NEXP - g < EG2) ? (NEXP - g) : EG2;
            ushort* wt2 = region;
            transpose_cvt_kernel<<<dim3(HID / 64, INTER / 64, ne), 256, 0, stream>>>(
                w2 + (size_t)g * IH, wt2, INTER, HID, ES);
            ffn2_kernel<<<NRB1 * ne * (HID / BN), 256, 0, stream>>>(
                h, wt2, cnt, pbase, wgtl, y, g, HID, 0);
        }
    }

    combine_kernel<<<T_TOKENS, 256, 0, stream>>>(y, pairrow, out);
}

// Round 12
// 844.934 us; speedup vs baseline: 1.6410x; 1.6410x over previous
//
#include <hip/hip_runtime.h>
#include <hip/hip_bf16.h>
#include <cstdint>

// MoEExperts: x[4096,2048] f32, top-2 of 8 experts,
// w1/w3 [8,2048,4096] (K-major [K][N]), w2 [8,4096,2048], out [4096,2048] f32.
#define T_TOKENS 4096
#define HID      2048
#define INTER    4096
#define NEXP     8
#define TOPK     2
#define NPAIRS   (T_TOKENS * TOPK)          // 8192
#define BM 128
#define BN 128
#define BK 32
#define MAXROWS  (NPAIRS + NEXP * BM)       // 9216
#define NRB1     64                          // worst-case per-expert row-blocks

typedef __attribute__((ext_vector_type(8))) short   short8;
typedef __attribute__((ext_vector_type(4))) float   f32x4;
typedef __attribute__((ext_vector_type(8))) ushort  ushort8v;

static __device__ __forceinline__ ushort f2bf(float f) {
    __hip_bfloat16 b = __float2bfloat16(f);
    return __builtin_bit_cast(ushort, b);
}

typedef const __attribute__((address_space(1))) unsigned char ga_u8;
typedef __attribute__((address_space(3))) unsigned char       la_u8;
static __device__ __forceinline__ void gl_lds16(const void* g, void* l) {
    __builtin_amdgcn_global_load_lds((ga_u8*)g, (la_u8*)l, 16, 0, 0);
}

// ---------------- routing -------------------------------------------------
__global__ void route_kernel(const int* __restrict__ eidx,
                             const float* __restrict__ ew,
                             int* __restrict__ cnt, int* __restrict__ pbase,
                             int* __restrict__ tokl, float* __restrict__ wgtl,
                             int* __restrict__ pairrow) {
    __shared__ int s_cnt[NEXP];
    __shared__ int s_pos[NEXP];
    __shared__ int s_base[NEXP];
    int tid = threadIdx.x;
    if (tid < NEXP) { s_cnt[tid] = 0; s_pos[tid] = 0; }
    __syncthreads();
    for (int p = tid; p < NPAIRS; p += blockDim.x)
        atomicAdd(&s_cnt[eidx[p]], 1);
    __syncthreads();
    if (tid == 0) {
        int b = 0;
        for (int e = 0; e < NEXP; ++e) {
            s_base[e] = b;
            cnt[e]    = s_cnt[e];
            pbase[e]  = b;
            b += (s_cnt[e] + BM - 1) / BM * BM;
        }
        pbase[NEXP] = b;
    }
    __syncthreads();
    for (int p = tid; p < NPAIRS; p += blockDim.x) {
        int e   = eidx[p];
        int pos = atomicAdd(&s_pos[e], 1);
        int row = s_base[e] + pos;
        tokl[row]  = p >> 1;
        wgtl[row]  = ew[p];
        pairrow[p] = row;
    }
}

// ---------------- x fp32 -> bf16 ------------------------------------------
__global__ __launch_bounds__(256) void cvt_x_kernel(const float* __restrict__ x,
                                                    ushort* __restrict__ xbf) {
    int i = (blockIdx.x * 256 + threadIdx.x) * 8;
    float4 a = *reinterpret_cast<const float4*>(x + i);
    float4 b = *reinterpret_cast<const float4*>(x + i + 4);
    ushort8v o;
    o[0] = f2bf(a.x); o[1] = f2bf(a.y); o[2] = f2bf(a.z); o[3] = f2bf(a.w);
    o[4] = f2bf(b.x); o[5] = f2bf(b.y); o[6] = f2bf(b.z); o[7] = f2bf(b.w);
    *reinterpret_cast<ushort8v*>(xbf + i) = o;
}

// ---------------- weight transpose+convert: fp32 [K][N] -> bf16 [N][K] -----
// Wide-coalescing version: wave reads 4 rows x 256B contiguous (vs 64B segs),
// writes 128B segs. LDS chunk-XOR swizzle keeps both LDS sides ~conflict-free.
// dst region layout: [z][CN][K]; src cols [c0, c0+CN). z<nA -> srcA else srcB.
#define TSW(n) (((n) >> 2) & 7)
__global__ __launch_bounds__(256) void transpose_cvt_kernel(
        const float* __restrict__ srcA, const float* __restrict__ srcB,
        ushort* __restrict__ dst, int K, int N, int c0, int CN,
        long estride, int nA) {
    __shared__ ushort t[64 * 72];
    int z = blockIdx.z;
    const float* s = (z < nA) ? (srcA + (size_t)z * estride)
                              : (srcB + (size_t)(z - nA) * estride);
    ushort* d = dst + (size_t)z * (size_t)CN * K;
    int nb = blockIdx.x * 64 + c0;
    int kb = blockIdx.y * 64;
    int tid = threadIdx.x;
    // read: 4 passes x 16 k-rows; 16 lanes x float4 per row = 256B/row
    int kr  = tid >> 4;          // 0..15
    int cc4 = tid & 15;          // float4 chunk within row
    #pragma unroll
    for (int p = 0; p < 4; ++p) {
        int k = kr + p * 16;
        float4 v = *reinterpret_cast<const float4*>(
            &s[(size_t)(kb + k) * N + nb + cc4 * 4]);
        ushort e[4] = { f2bf(v.x), f2bf(v.y), f2bf(v.z), f2bf(v.w) };
        #pragma unroll
        for (int j = 0; j < 4; ++j) {
            int n = cc4 * 4 + j;
            t[n * 72 + (k & 7) + (((k >> 3) ^ TSW(n)) << 3)] = e[j];
        }
    }
    __syncthreads();
    // write: 2 passes x 32 n-rows; 8 lanes x 16B per row = 128B/row
    int nr  = tid >> 3;          // 0..31
    int cc8 = tid & 7;
    #pragma unroll
    for (int p = 0; p < 2; ++p) {
        int n = nr + p * 32;
        ushort8v v8 = *reinterpret_cast<const ushort8v*>(
            &t[n * 72 + ((cc8 ^ TSW(n)) << 3)]);
        *reinterpret_cast<ushort8v*>(
            &d[(size_t)(nb - c0 + n) * K + kb + cc8 * 8]) = v8;
    }
}

// swizzle helper: spreads 16B slots across banks; bijective per row
#define SWZV(r) (((r) & 3) ^ (((r) >> 2) & 3))

// ---------------- ffn1: h = silu(x@w1) * (x@w3) ----------------------------
#define F1_LDSB 24576   // per dbuf: A 8KB + B1 8KB + B3 8KB
__global__ __launch_bounds__(256, 2) void ffn1_kernel(
        const ushort* __restrict__ xbf,
        const ushort* __restrict__ wT1, const ushort* __restrict__ wT3,
        const int* __restrict__ cnt, const int* __restrict__ pbase,
        const int* __restrict__ tokl, ushort* __restrict__ h,
        int e0, int CN, int c0) {
    int d = blockIdx.x;
    int xcd = d & 7, q = d >> 3;
    int gq = q / NRB1, rb = q % NRB1;
    int ncb = CN >> 7;
    int g = gq * 8 + xcd;
    int ez = g / ncb, cb = g - ez * ncb;
    int e = e0 + ez;
    int ce = cnt[e];
    int r0 = rb * BM;
    if (r0 >= ce) return;
    int base = pbase[e];

    __shared__ ushort ldsbuf[2 * F1_LDSB / 2];
    int tid = threadIdx.x, lane = tid & 63, wid = tid >> 6;
    int wr = (wid >> 1) * 64, wc = (wid & 1) * 64;

    int t0 = wid * 32 + (lane >> 2);
    int t1 = t0 + 16;
    int sw0 = (((lane & 3) ^ SWZV(t0)) << 4);
    int sw1 = (((lane & 3) ^ SWZV(t1)) << 4);
    int cr0 = r0 + t0, cr1 = r0 + t1;
    const char* aS0 = (const char*)(xbf + (size_t)tokl[base + (cr0 < ce ? cr0 : 0)] * HID) + sw0;
    const char* aS1 = (const char*)(xbf + (size_t)tokl[base + (cr1 < ce ? cr1 : 0)] * HID) + sw1;
    const ushort* B1g = wT1 + ((size_t)ez * CN + (size_t)cb * 128) * HID;
    const ushort* B3g = wT3 + ((size_t)ez * CN + (size_t)cb * 128) * HID;
    const char* b1S0 = (const char*)(B1g + (size_t)t0 * HID) + sw0;
    const char* b1S1 = (const char*)(B1g + (size_t)t1 * HID) + sw1;
    const char* b3S0 = (const char*)(B3g + (size_t)t0 * HID) + sw0;
    const char* b3S1 = (const char*)(B3g + (size_t)t1 * HID) + sw1;

    char* Lb = (char*)ldsbuf;
    int dst0 = wid * 2048;

    int vl = SWZV(lane & 15);
    int fs = (((lane >> 4) ^ vl) << 4);
    int aoff[4], boff[4];
    #pragma unroll
    for (int i = 0; i < 4; ++i) {
        aoff[i] = (wr + i * 16 + (lane & 15)) * 64 + fs;
        boff[i] = (wc + i * 16 + (lane & 15)) * 64 + fs;
    }

    f32x4 accg[4][4], accu[4][4];
    #pragma unroll
    for (int i = 0; i < 4; ++i)
        #pragma unroll
        for (int j = 0; j < 4; ++j) { accg[i][j] = (f32x4)0.f; accu[i][j] = (f32x4)0.f; }

    auto stage = [&](int buf, int t) {
        char* L = Lb + buf * F1_LDSB;
        int adv = t * 64;
        gl_lds16(aS0 + adv,  L + dst0);
        gl_lds16(aS1 + adv,  L + dst0 + 1024);
        gl_lds16(b1S0 + adv, L + 8192 + dst0);
        gl_lds16(b1S1 + adv, L + 8192 + dst0 + 1024);
        gl_lds16(b3S0 + adv, L + 16384 + dst0);
        gl_lds16(b3S1 + adv, L + 16384 + dst0 + 1024);
    };

    stage(0, 0);
    __syncthreads();
    const int NT = HID / BK;
    for (int t = 0; t < NT; ++t) {
        int cur = t & 1;
        if (t + 1 < NT) stage(cur ^ 1, t + 1);
        const char* L = Lb + cur * F1_LDSB;
        short8 af[4];
        #pragma unroll
        for (int mi = 0; mi < 4; ++mi)
            af[mi] = *reinterpret_cast<const short8*>(L + aoff[mi]);
        #pragma unroll
        for (int ni = 0; ni < 4; ++ni) {
            short8 b1 = *reinterpret_cast<const short8*>(L + 8192 + boff[ni]);
            short8 b3 = *reinterpret_cast<const short8*>(L + 16384 + boff[ni]);
            #pragma unroll
            for (int mi = 0; mi < 4; ++mi) {
                accg[mi][ni] = __builtin_amdgcn_mfma_f32_16x16x32_bf16(af[mi], b1, accg[mi][ni], 0, 0, 0);
                accu[mi][ni] = __builtin_amdgcn_mfma_f32_16x16x32_bf16(af[mi], b3, accu[mi][ni], 0, 0, 0);
            }
        }
        __syncthreads();
    }

    int hcol = c0 + cb * 128 + wc + (lane & 15);
    #pragma unroll
    for (int mi = 0; mi < 4; ++mi) {
        #pragma unroll
        for (int q2 = 0; q2 < 4; ++q2) {
            int r = r0 + wr + mi * 16 + (lane >> 4) * 4 + q2;
            if (r >= ce) continue;
            ushort* hp = h + (size_t)(base + r) * INTER + hcol;
            #pragma unroll
            for (int ni = 0; ni < 4; ++ni) {
                float gg = accg[mi][ni][q2];
                float uu = accu[mi][ni][q2];
                float s = gg / (1.f + __expf(-gg));
                hp[ni * 16] = f2bf(s * uu);
            }
        }
    }
}

// ---------------- ffn2: y = wgt * (h @ w2) ---------------------------------
#define F2_LDSB 16384   // per dbuf: A 8KB + B 8KB
__global__ __launch_bounds__(256, 3) void ffn2_kernel(
        const ushort* __restrict__ h,
        const ushort* __restrict__ wT2,
        const int* __restrict__ cnt, const int* __restrict__ pbase,
        const float* __restrict__ wgtl, ushort* __restrict__ y,
        int e0, int CN, int c0) {
    int d = blockIdx.x;
    int xcd = d & 7, q = d >> 3;
    int gq = q / NRB1, rb = q % NRB1;
    int ncb = CN >> 7;
    int g = gq * 8 + xcd;
    int ez = g / ncb, cb = g - ez * ncb;
    int e = e0 + ez;
    int ce = cnt[e];
    int r0 = rb * BM;
    if (r0 >= ce) return;
    int base = pbase[e];

    __shared__ ushort ldsbuf[2 * F2_LDSB / 2];
    int tid = threadIdx.x, lane = tid & 63, wid = tid >> 6;
    int wr = (wid >> 1) * 64, wc = (wid & 1) * 64;

    int t0 = wid * 32 + (lane >> 2);
    int t1 = t0 + 16;
    int sw0 = (((lane & 3) ^ SWZV(t0)) << 4);
    int sw1 = (((lane & 3) ^ SWZV(t1)) << 4);
    int cr0 = r0 + t0, cr1 = r0 + t1;
    const char* aS0 = (const char*)(h + (size_t)(base + (cr0 < ce ? cr0 : 0)) * INTER) + sw0;
    const char* aS1 = (const char*)(h + (size_t)(base + (cr1 < ce ? cr1 : 0)) * INTER) + sw1;
    const ushort* Bg = wT2 + ((size_t)ez * CN + (size_t)cb * 128) * INTER;
    const char* bS0 = (const char*)(Bg + (size_t)t0 * INTER) + sw0;
    const char* bS1 = (const char*)(Bg + (size_t)t1 * INTER) + sw1;

    char* Lb = (char*)ldsbuf;
    int dst0 = wid * 2048;

    int vl = SWZV(lane & 15);
    int fs = (((lane >> 4) ^ vl) << 4);
    int aoff[4], boff[4];
    #pragma unroll
    for (int i = 0; i < 4; ++i) {
        aoff[i] = (wr + i * 16 + (lane & 15)) * 64 + fs;
        boff[i] = (wc + i * 16 + (lane & 15)) * 64 + fs;
    }

    f32x4 acc[4][4];
    #pragma unroll
    for (int i = 0; i < 4; ++i)
        #pragma unroll
        for (int j = 0; j < 4; ++j) acc[i][j] = (f32x4)0.f;

    auto stage = [&](int buf, int t) {
        char* L = Lb + buf * F2_LDSB;
        int adv = t * 64;
        gl_lds16(aS0 + adv, L + dst0);
        gl_lds16(aS1 + adv, L + dst0 + 1024);
        gl_lds16(bS0 + adv, L + 8192 + dst0);
        gl_lds16(bS1 + adv, L + 8192 + dst0 + 1024);
    };

    stage(0, 0);
    __syncthreads();
    const int NT = INTER / BK;
    for (int t = 0; t < NT; ++t) {
        int cur = t & 1;
        if (t + 1 < NT) stage(cur ^ 1, t + 1);
        const char* L = Lb + cur * F2_LDSB;
        short8 af[4];
        #pragma unroll
        for (int mi = 0; mi < 4; ++mi)
            af[mi] = *reinterpret_cast<const short8*>(L + aoff[mi]);
        #pragma unroll
        for (int ni = 0; ni < 4; ++ni) {
            short8 b = *reinterpret_cast<const short8*>(L + 8192 + boff[ni]);
            #pragma unroll
            for (int mi = 0; mi < 4; ++mi)
                acc[mi][ni] = __builtin_amdgcn_mfma_f32_16x16x32_bf16(af[mi], b, acc[mi][ni], 0, 0, 0);
        }
        __syncthreads();
    }

    int ycol = c0 + cb * 128 + wc + (lane & 15);
    #pragma unroll
    for (int mi = 0; mi < 4; ++mi) {
        #pragma unroll
        for (int q2 = 0; q2 < 4; ++q2) {
            int r = r0 + wr + mi * 16 + (lane >> 4) * 4 + q2;
            if (r >= ce) continue;
            float wv = wgtl[base + r];
            ushort* yp = y + (size_t)(base + r) * HID + ycol;
            #pragma unroll
            for (int ni = 0; ni < 4; ++ni)
                yp[ni * 16] = f2bf(wv * acc[mi][ni][q2]);
        }
    }
}

// ---------------- combine --------------------------------------------------
__global__ __launch_bounds__(256) void combine_kernel(
        const ushort* __restrict__ y, const int* __restrict__ pairrow,
        float* __restrict__ out) {
    int t = blockIdx.x;
    const ushort* y0 = y + (size_t)pairrow[2 * t] * HID;
    const ushort* y1 = y + (size_t)pairrow[2 * t + 1] * HID;
    float* op = out + (size_t)t * HID;
    int c = threadIdx.x * 8;
    uint4 a = *reinterpret_cast<const uint4*>(y0 + c);
    uint4 b = *reinterpret_cast<const uint4*>(y1 + c);
    const uint* au = reinterpret_cast<const uint*>(&a);
    const uint* bu = reinterpret_cast<const uint*>(&b);
    #pragma unroll
    for (int i = 0; i < 4; ++i) {
        float alo = __builtin_bit_cast(float, au[i] << 16);
        float ahi = __builtin_bit_cast(float, au[i] & 0xffff0000u);
        float blo = __builtin_bit_cast(float, bu[i] << 16);
        float bhi = __builtin_bit_cast(float, bu[i] & 0xffff0000u);
        op[c + 2 * i]     = alo + blo;
        op[c + 2 * i + 1] = ahi + bhi;
    }
}

extern "C" void kernel_launch(void* const* d_in, const int* in_sizes, int n_in,
                              void* d_out, int out_size, void* d_ws, size_t ws_size,
                              hipStream_t stream) {
    (void)in_sizes; (void)n_in; (void)out_size;
    const float* x   = (const float*)d_in[0];
    const float* ew  = (const float*)d_in[1];
    const float* w1  = (const float*)d_in[2];
    const float* w2  = (const float*)d_in[3];
    const float* w3  = (const float*)d_in[4];
    const int*  eidx = (const int*)d_in[5];
    float* out = (float*)d_out;

    int*   cnt     = (int*)d_ws;
    int*   pbase   = cnt + 8;
    int*   tokl    = cnt + 32;
    float* wgtl    = (float*)(tokl + MAXROWS);
    int*   pairrow = (int*)(wgtl + MAXROWS);
    ushort* xbf = (ushort*)((((uintptr_t)(pairrow + NPAIRS)) + 255) & ~(uintptr_t)255);
    ushort* h   = xbf + (size_t)T_TOKENS * HID;
    ushort* y   = h + (size_t)MAXROWS * INTER;
    ushort* region = y + (size_t)MAXROWS * HID;
    size_t region_bytes = ws_size - ((char*)region - (char*)d_ws);

    const size_t IH = (size_t)INTER * HID;
    const long   ES = (long)HID * INTER;

    route_kernel<<<1, 256, 0, stream>>>(eidx, ew, cnt, pbase, tokl, wgtl, pairrow);
    cvt_x_kernel<<<T_TOKENS * HID / 8 / 256, 256, 0, stream>>>(x, xbf);

    const size_t per_e1 = 2 * IH * sizeof(ushort);   // 33.55 MB (w1T+w3T per expert)
    const size_t per_e2 = IH * sizeof(ushort);       // 16.78 MB

    // ---- stage 1: transpose w1/w3 (merged launch) + ffn1 ----
    if (region_bytes >= per_e1) {
        int EG = (int)(region_bytes / per_e1); if (EG > 8) EG = 8;
        for (int g = 0; g < NEXP; g += EG) {
            int ne = (NEXP - g < EG) ? (NEXP - g) : EG;
            ushort* wt1 = region;                      // [ne][INTER][HID]
            ushort* wt3 = region + (size_t)ne * IH;
            transpose_cvt_kernel<<<dim3(INTER / 64, HID / 64, 2 * ne), 256, 0, stream>>>(
                w1 + (size_t)g * IH, w3 + (size_t)g * IH, wt1,
                HID, INTER, 0, INTER, ES, ne);
            ffn1_kernel<<<NRB1 * ne * (INTER / BN), 256, 0, stream>>>(
                xbf, wt1, wt3, cnt, pbase, tokl, h, g, INTER, 0);
        }
    } else {
        const int CN = 1024;
        for (int e = 0; e < NEXP; ++e) {
            for (int c = 0; c < INTER; c += CN) {
                ushort* wt1 = region;
                ushort* wt3 = region + (size_t)CN * HID;
                transpose_cvt_kernel<<<dim3(CN / 64, HID / 64, 2), 256, 0, stream>>>(
                    w1 + (size_t)e * IH, w3 + (size_t)e * IH, wt1,
                    HID, INTER, c, CN, 0, 1);
                ffn1_kernel<<<NRB1 * (CN / BN), 256, 0, stream>>>(
                    xbf, wt1, wt3, cnt, pbase, tokl, h, e, CN, c);
            }
        }
    }

    // ---- stage 2: transpose w2 + ffn2 ----
    if (region_bytes >= per_e2) {
        int EG = (int)(region_bytes / per_e2); if (EG > 8) EG = 8;
        for (int g = 0; g < NEXP; g += EG) {
            int ne = (NEXP - g < EG) ? (NEXP - g) : EG;
            ushort* wt2 = region;
            transpose_cvt_kernel<<<dim3(HID / 64, INTER / 64, ne), 256, 0, stream>>>(
                w2 + (size_t)g * IH, w2 + (size_t)g * IH, wt2,
                INTER, HID, 0, HID, ES, ne);
            ffn2_kernel<<<NRB1 * ne * (HID / BN), 256, 0, stream>>>(
                h, wt2, cnt, pbase, wgtl, y, g, HID, 0);
        }
    } else {
        const int CN = 1024;
        for (int e = 0; e < NEXP; ++e) {
            for (int c = 0; c < HID; c += CN) {
                ushort* wt2 = region;
                transpose_cvt_kernel<<<dim3(CN / 64, INTER / 64, 1), 256, 0, stream>>>(
                    w2 + (size_t)e * IH, w2 + (size_t)e * IH, wt2,
                    INTER, HID, c, CN, 0, 1);
                ffn2_kernel<<<NRB1 * (CN / BN), 256, 0, stream>>>(
                    h, wt2, cnt, pbase, wgtl, y, e, CN, c);
            }
        }
    }

    combine_kernel<<<T_TOKENS, 256, 0, stream>>>(y, pairrow, out);
}